// Round 1
// 961.240 us; speedup vs baseline: 1.0418x; 1.0418x over previous
//
#include <hip/hip_runtime.h>
#include <hip/hip_bf16.h>
#include <hip/hip_fp16.h>
#include <cstdint>

typedef __hip_bfloat16 bf16;
typedef __attribute__((ext_vector_type(8))) short frag_ab;   // 8 bf16 (4 VGPRs)
typedef __attribute__((ext_vector_type(4))) float frag_cd;   // 4 fp32
typedef __attribute__((ext_vector_type(4))) short short4v;   // 4 x 16-bit
typedef __attribute__((ext_vector_type(8))) short short8v;   // 8 x 16-bit (16B)
typedef unsigned short u16;

__device__ __forceinline__ float b2f(short s){
  return __uint_as_float(((unsigned)(unsigned short)s) << 16);
}
__device__ __forceinline__ float h2f(short s){
  __half h; __builtin_memcpy(&h, &s, 2); return __half2float(h);
}
__device__ __forceinline__ short f2h_s(float x){
  __half h = __float2half(x);
  short s; __builtin_memcpy(&s, &h, 2); return s;
}
__device__ __forceinline__ void bf_split(float x, short& hi, short& lo){
  bf16 h = __float2bfloat16(x);
  float hf = __bfloat162float(h);
  bf16 l = __float2bfloat16(x - hf);
  __builtin_memcpy(&hi, &h, 2);
  __builtin_memcpy(&lo, &l, 2);
}

__device__ __forceinline__ float wave_sum(float v){
#pragma unroll
  for (int o = 32; o > 0; o >>= 1) v += __shfl_down(v, o, 64);
  return v;
}

// ---- fused copy-in: eu/ei f32 [n,64] -> strided [n,192] f32 (+ optional f16 table) ----
__global__ void k_copy_in2(const float* __restrict__ eu, const float* __restrict__ ei,
                           float* __restrict__ hu, float* __restrict__ hi,
                           __half* __restrict__ huf, __half* __restrict__ hif,
                           int NU, int NI){
  int idx = blockIdx.x * 256 + threadIdx.x;   // one float4 per thread
  int tu = NU * 16;
  if (idx >= tu + NI * 16) return;
  const float* srcp; float* dstp; __half* fp_; int r, jj;
  if (idx < tu){ r = idx >> 4; jj = idx & 15; srcp = eu; dstp = hu; fp_ = huf; }
  else { int t = idx - tu; r = t >> 4; jj = t & 15; srcp = ei; dstp = hi; fp_ = hif; }
  float4 v = *(const float4*)(srcp + (size_t)r * 64 + 4 * jj);
  *(float4*)(dstp + (size_t)r * 192 + 4 * jj) = v;
  if (fp_){
    short4v h;
    h[0] = f2h_s(v.x); h[1] = f2h_s(v.y); h[2] = f2h_s(v.z); h[3] = f2h_s(v.w);
    *(short4v*)((short*)fp_ + (size_t)r * 192 + 4 * jj) = h;
  }
}

// ---- pre-split all 12 W matrices into MFMA-fragment-ordered bf16 hi/lo ----
__global__ void k_wsplit(const float* __restrict__ rateW, const float* __restrict__ rbW,
                         const float* __restrict__ trW,
                         short* __restrict__ Whi, short* __restrict__ Wlo){
  int tid = blockIdx.x * 256 + threadIdx.x;       // 12*4096 total
  if (tid >= 12 * 4096) return;
  int m = tid >> 12, rem = tid & 4095;
  int lane = rem >> 6, rem2 = rem & 63;
  int pair = rem2 >> 3, j = rem2 & 7;
  int c = pair >> 1, h = pair & 1;
  int rel = m >> 2, li = m & 3;                    // li = l*2+io
  const float* base = (rel == 0) ? rateW : (rel == 1) ? rbW : trW;
  float v = base[(size_t)li * 4096 + (32 * h + (lane >> 4) * 8 + j) * 64 + 16 * c + (lane & 15)];
  short sh, sl; bf_split(v, sh, sl);
  Whi[tid] = sh; Wlo[tid] = sl;
}

// ---- fused multi-output linear: out_i = bf16(x @ W_i + b_i), i<mcount ----
__global__ void k_linear_multi(const float* __restrict__ x, int xs, int xo, int n,
                               const short* __restrict__ Whi, const short* __restrict__ Wlo,
                               int mcount,
                               int m0, const float* __restrict__ b0, bf16* __restrict__ o0,
                               int m1, const float* __restrict__ b1, bf16* __restrict__ o1,
                               int m2, const float* __restrict__ b2, bf16* __restrict__ o2,
                               int m3, const float* __restrict__ b3, bf16* __restrict__ o3){
  int lane = threadIdx.x & 63, w = threadIdx.x >> 6;
  int quad = lane >> 4, n16 = lane & 15;
  int rowbase = blockIdx.x * 64 + w * 16;
  if (rowbase >= n) return;
  int lrow = rowbase + n16; if (lrow >= n) lrow = n - 1;   // clamp (stores guarded)
  const float* xp = x + (size_t)lrow * xs + xo;
  frag_ab ahi[2], alo[2];
#pragma unroll
  for (int h = 0; h < 2; ++h){
    frag_ab vh, vl;
#pragma unroll
    for (int j = 0; j < 8; ++j){
      float xv = xp[32 * h + quad * 8 + j];
      short sh, sl; bf_split(xv, sh, sl);
      vh[j] = sh; vl[j] = sl;
    }
    ahi[h] = vh; alo[h] = vl;
  }
  int ms[4] = {m0, m1, m2, m3};
  const float* bs[4] = {b0, b1, b2, b3};
  bf16* os[4] = {o0, o1, o2, o3};
  for (int i = 0; i < mcount; ++i){
    const frag_ab* Bh = (const frag_ab*)(Whi + (size_t)ms[i] * 4096 + lane * 64);
    const frag_ab* Bl = (const frag_ab*)(Wlo + (size_t)ms[i] * 4096 + lane * 64);
    frag_cd acc[4];
#pragma unroll
    for (int c = 0; c < 4; ++c) acc[c] = frag_cd{0.f, 0.f, 0.f, 0.f};
#pragma unroll
    for (int c = 0; c < 4; ++c)
#pragma unroll
      for (int h = 0; h < 2; ++h){
        frag_ab bh = Bh[c * 2 + h], bl = Bl[c * 2 + h];
        acc[c] = __builtin_amdgcn_mfma_f32_16x16x32_bf16(ahi[h], bh, acc[c], 0, 0, 0);
        acc[c] = __builtin_amdgcn_mfma_f32_16x16x32_bf16(alo[h], bh, acc[c], 0, 0, 0);
        acc[c] = __builtin_amdgcn_mfma_f32_16x16x32_bf16(ahi[h], bl, acc[c], 0, 0, 0);
      }
    const float* bb = bs[i];
    bf16* oo = os[i];
#pragma unroll
    for (int reg = 0; reg < 4; ++reg){
      int r = rowbase + quad * 4 + reg;
      if (r >= n) continue;
#pragma unroll
      for (int c = 0; c < 4; ++c)
        oo[(size_t)r * 64 + 16 * c + n16] = __float2bfloat16(acc[c][reg] + bb[16 * c + n16]);
    }
  }
}

// ================= CSR build =================
// fused histogram+position for all three edge lists; pos stored u16 (max degree << 64K)
__global__ void k_hist_all(const int* __restrict__ rate_src, const int* __restrict__ rate_dst,
                           const int* __restrict__ trust_dst,
                           int* __restrict__ cntA, int* __restrict__ cntB,
                           int* __restrict__ cntC,
                           u16* __restrict__ posA, u16* __restrict__ posB,
                           u16* __restrict__ posC, int ER, int ET){
  int k = blockIdx.x * 256 + threadIdx.x;
  if (k < ER){
    int d = rate_dst[k], s = rate_src[k];
    posA[k] = (u16)atomicAdd(cntA + d, 1);
    posB[k] = (u16)atomicAdd(cntB + s, 1);
  }
  if (k < ET){
    posC[k] = (u16)atomicAdd(cntC + trust_dst[k], 1);
  }
}

// multi-block scan: block grabs contiguous range via atomicAdd on gbase.
__global__ void k_scan_mb(const int* __restrict__ cnt, int n,
                          int* __restrict__ offs, int* __restrict__ gbase){
  __shared__ int wsum[16];
  __shared__ int base_sh;
  int t = threadIdx.x, lane = t & 63, w = t >> 6;
  int i = blockIdx.x * 1024 + t;
  int v = (i < n) ? cnt[i] : 0;
  int x = v;
#pragma unroll
  for (int o = 1; o < 64; o <<= 1){
    int y = __shfl_up(x, o, 64);
    if (lane >= o) x += y;
  }
  if (lane == 63) wsum[w] = x;
  __syncthreads();
  if (t == 0){
    int tot = 0;
    for (int k = 0; k < 16; ++k){ int c = wsum[k]; wsum[k] = tot; tot += c; }
    base_sh = atomicAdd(gbase, tot);
  }
  __syncthreads();
  if (i < n) offs[i] = base_sh + wsum[w] + x - v;
}

// atomic-free fused fill: position known, pure gather+scatter
__global__ void k_fill_all(const int* __restrict__ rate_src, const int* __restrict__ rate_dst,
                           const int* __restrict__ trust_src, const int* __restrict__ trust_dst,
                           const int* __restrict__ offsA, const u16* __restrict__ posA,
                           int* __restrict__ csrA,
                           const int* __restrict__ offsB, const u16* __restrict__ posB,
                           int* __restrict__ csrB,
                           const int* __restrict__ offsC, const u16* __restrict__ posC,
                           int* __restrict__ csrC, int ER, int ET){
  int k = blockIdx.x * 256 + threadIdx.x;
  if (k < ER){
    int s = rate_src[k], d = rate_dst[k];
    csrA[offsA[d] + (int)posA[k]] = s;
    csrB[offsB[s] + (int)posB[k]] = d;
  }
  if (k < ET){
    int s = trust_src[k], d = trust_dst[k];
    csrC[offsC[d] + (int)posC[k]] = s;
  }
}

// ============ fused GATv2 aggregation: 8 lanes/edge, 8 edges per wave ============
// fout (optional, pre-offset by column block) additionally stores fp16 score-table copy.
__global__ void k_gat(const int* __restrict__ offs, const int* __restrict__ cnt,
                      const int* __restrict__ csr_src,
                      const bf16* __restrict__ fs, const bf16* __restrict__ fd,
                      const float* __restrict__ attn, const float* __restrict__ bias,
                      float* __restrict__ out, int os, int oo,
                      const float* __restrict__ res, int rs, int ro,
                      __half* __restrict__ fout, int n){
  int d = blockIdx.x * 4 + (threadIdx.x >> 6);
  if (d >= n) return;
  int lane = threadIdx.x & 63;
  int g = lane >> 3, l8 = lane & 7;          // 8 groups x 8 lanes; lane covers 8 cols
  short8v dv = *(const short8v*)(fd + (size_t)d * 64 + 8 * l8);
  float fdv[8];
#pragma unroll
  for (int j = 0; j < 8; ++j) fdv[j] = b2f(dv[j]);
  float4 a0 = *(const float4*)(attn + 8 * l8);
  float4 a1 = *(const float4*)(attn + 8 * l8 + 4);
  float a8[8] = {a0.x, a0.y, a0.z, a0.w, a1.x, a1.y, a1.z, a1.w};
  float acc[8];
#pragma unroll
  for (int j = 0; j < 8; ++j) acc[j] = 0.f;
  float den = 0.f;
  int idx0 = offs[d], end = idx0 + cnt[d];
  for (int idx = idx0; idx < end; idx += 8){
    int e = idx + g;
    bool valid = e < end;
    int s = csr_src[valid ? e : idx];
    short8v sv = *(const short8v*)(fs + (size_t)s * 64 + 8 * l8);
    float f[8];
    float tt = 0.f;
#pragma unroll
    for (int j = 0; j < 8; ++j){
      f[j] = b2f(sv[j]);
      float v = f[j] + fdv[j];
      v = (v > 0.f) ? v : 0.2f * v;
      tt += v * a8[j];
    }
#pragma unroll
    for (int o = 1; o < 8; o <<= 1) tt += __shfl_xor(tt, o, 64);
    float ex = valid ? __expf(tt) : 0.f;
#pragma unroll
    for (int j = 0; j < 8; ++j) acc[j] += ex * f[j];
    den += ex;
  }
#pragma unroll
  for (int o = 8; o < 64; o <<= 1){
#pragma unroll
    for (int j = 0; j < 8; ++j) acc[j] += __shfl_xor(acc[j], o, 64);
    den += __shfl_xor(den, o, 64);
  }
  if (g == 0){
    float inv = (den > 0.f) ? 1.f / den : 0.f;
    float4 b0 = *(const float4*)(bias + 8 * l8);
    float4 b1 = *(const float4*)(bias + 8 * l8 + 4);
    float o8[8];
    o8[0] = acc[0] * inv + b0.x; o8[1] = acc[1] * inv + b0.y;
    o8[2] = acc[2] * inv + b0.z; o8[3] = acc[3] * inv + b0.w;
    o8[4] = acc[4] * inv + b1.x; o8[5] = acc[5] * inv + b1.y;
    o8[6] = acc[6] * inv + b1.z; o8[7] = acc[7] * inv + b1.w;
    if (res){
      float4 r0 = *(const float4*)(res + (size_t)d * rs + ro + 8 * l8);
      float4 r1 = *(const float4*)(res + (size_t)d * rs + ro + 8 * l8 + 4);
      o8[0] += r0.x; o8[1] += r0.y; o8[2] += r0.z; o8[3] += r0.w;
      o8[4] += r1.x; o8[5] += r1.y; o8[6] += r1.z; o8[7] += r1.w;
    }
    *(float4*)(out + (size_t)d * os + oo + 8 * l8) = make_float4(o8[0], o8[1], o8[2], o8[3]);
    *(float4*)(out + (size_t)d * os + oo + 8 * l8 + 4) = make_float4(o8[4], o8[5], o8[6], o8[7]);
    if (fout){
      short8v hv;
#pragma unroll
      for (int j = 0; j < 8; ++j) hv[j] = f2h_s(o8[j]);
      *(short8v*)((short*)fout + (size_t)d * 192 + 8 * l8) = hv;
    }
  }
}

// ---- collapse attention-gate MLP: v = W1@W2 (per l,i), c = b1@W2 + b2 ----
__global__ void k_attvec(const float* __restrict__ W1, const float* __restrict__ b1,
                         const float* __restrict__ W2, const float* __restrict__ b2,
                         float* __restrict__ vvec, float* __restrict__ cs){
  int t = threadIdx.x;
  int li = t >> 7, r = t & 127;
  float acc = 0.f;
  for (int c = 0; c < 128; ++c)
    acc += W1[(size_t)(li * 128 + r) * 128 + c] * W2[li * 128 + c];
  vvec[li * 128 + r] = acc;
  if (r == 0){
    float cacc = b2[li];
    for (int c = 0; c < 128; ++c)
      cacc += b1[li * 128 + c] * W2[li * 128 + c];
    cs[li] = cacc;
  }
}

// ---- gate z-scores + per-block partial sums for BatchNorm ----
__global__ void k_gate_z(const float* __restrict__ hu_all, int l,
                         const float* __restrict__ p, const float* __restrict__ q,
                         const float* __restrict__ vvec, const float* __restrict__ cs,
                         float* __restrict__ z1, float* __restrict__ z2,
                         float* __restrict__ bsums, int n){
  __shared__ float part[4][4];
  int w = threadIdx.x >> 6, j = threadIdx.x & 63;
  int nidx = blockIdx.x * 4 + w;
  float lz1 = 0.f, lz2 = 0.f;
  if (nidx < n){
    const float* v1 = vvec + l * 256;
    const float* v2 = vvec + l * 256 + 128;
    float h  = hu_all[(size_t)nidx * 192 + l * 64 + j];
    float pv = p[(size_t)nidx * 64 + j];
    float qv = q[(size_t)nidx * 64 + j];
    float t1 = wave_sum(h * v1[j] + pv * v1[64 + j]);
    float t2 = wave_sum(h * v2[j] + qv * v2[64 + j]);
    if (j == 0){
      lz1 = t1 + cs[l * 2 + 0];
      lz2 = t2 + cs[l * 2 + 1];
      z1[nidx] = lz1;
      z2[nidx] = lz2;
    }
  }
  if (j == 0){
    part[w][0] = lz1; part[w][1] = lz1 * lz1;
    part[w][2] = lz2; part[w][3] = lz2 * lz2;
  }
  __syncthreads();
  if (threadIdx.x < 4)
    bsums[(size_t)blockIdx.x * 4 + threadIdx.x] =
        part[0][threadIdx.x] + part[1][threadIdx.x] +
        part[2][threadIdx.x] + part[3][threadIdx.x];
}

// ---- BN reduce stage 1: 128 blocks grid-stride -> gpart[128][4] ----
__global__ void k_bn_part(const float* __restrict__ bsums, int nb,
                          double* __restrict__ gpart){
  __shared__ double sh[256];
  int c = threadIdx.x & 3, r0 = blockIdx.x * 64 + (threadIdx.x >> 2);
  double acc = 0.0;
  for (int i = r0; i < nb; i += gridDim.x * 64)
    acc += (double)bsums[(size_t)i * 4 + c];
  sh[threadIdx.x] = acc;
  __syncthreads();
  for (int s = 128; s >= 4; s >>= 1){
    if (threadIdx.x < s) sh[threadIdx.x] += sh[threadIdx.x + s];
    __syncthreads();
  }
  if (threadIdx.x < 4) gpart[(size_t)blockIdx.x * 4 + threadIdx.x] = sh[threadIdx.x];
}

// ---- BN reduce stage 2: single block over 128 partials -> sums[4] ----
__global__ void k_bn_final(const double* __restrict__ gpart, int nbk,
                           double* __restrict__ sums){
  __shared__ double sh[256];
  int c = threadIdx.x & 3, k0 = threadIdx.x >> 2;
  double acc = 0.0;
  for (int i = k0; i < nbk; i += 64) acc += gpart[(size_t)i * 4 + c];
  sh[threadIdx.x] = acc;
  __syncthreads();
  for (int s = 128; s >= 4; s >>= 1){
    if (threadIdx.x < s) sh[threadIdx.x] += sh[threadIdx.x + s];
    __syncthreads();
  }
  if (threadIdx.x < 4) sums[threadIdx.x] = sh[threadIdx.x];
}

// ---- BN + lrelu(0.01) + softmax gate + residual combine (+ optional f16 table) ----
__global__ void k_gate_combine(float* __restrict__ hu_all, int l,
                               const float* __restrict__ p, const float* __restrict__ q,
                               const float* __restrict__ z1, const float* __restrict__ z2,
                               const double* __restrict__ sums,
                               __half* __restrict__ fout, int wf32, int n){
  int idx = blockIdx.x * 256 + threadIdx.x;
  if (idx >= n * 64) return;
  int r = idx >> 6, j = idx & 63;
  double invn = 1.0 / (double)n;
  double mu1 = sums[0] * invn, mu2 = sums[2] * invn;
  float var1 = (float)(sums[1] * invn - mu1 * mu1);
  float var2 = (float)(sums[3] * invn - mu2 * mu2);
  float rs1 = rsqrtf(var1 + 1e-5f), rs2 = rsqrtf(var2 + 1e-5f);
  float a1 = (z1[r] - (float)mu1) * rs1;
  float a2 = (z2[r] - (float)mu2) * rs2;
  a1 = a1 > 0.f ? a1 : 0.01f * a1;
  a2 = a2 > 0.f ? a2 : 0.01f * a2;
  float mx = fmaxf(a1, a2);
  float e1 = __expf(a1 - mx), e2 = __expf(a2 - mx);
  float inv = 1.f / (e1 + e2);
  float out = (e1 * inv) * p[idx] + (e2 * inv) * q[idx]
            + hu_all[(size_t)r * 192 + l * 64 + j];
  if (wf32) hu_all[(size_t)r * 192 + (l + 1) * 64 + j] = out;
  if (fout) *((short*)fout + (size_t)r * 192 + j) = f2h_s(out);
}

// ---- final scoring, fp16 tables: 8 pairs per wave (8 lanes each), 16B loads ----
__global__ void k_score_f16(const int* __restrict__ pu, const int* __restrict__ pi,
                            const int* __restrict__ nu, const int* __restrict__ ni,
                            const __half* __restrict__ huf, const __half* __restrict__ hif,
                            float* __restrict__ out, int EP){
  int wv = threadIdx.x >> 6, lane = threadIdx.x & 63;
  int g = lane >> 3, l8 = lane & 7;
  int k = (blockIdx.x * 4 + wv) * 8 + g;
  if (k >= 2 * EP) return;
  int u, i;
  if (k < EP){ u = pu[k]; i = pi[k]; } else { u = nu[k - EP]; i = ni[k - EP]; }
  const short8v* hu = (const short8v*)(huf + (size_t)u * 192);
  const short8v* hi = (const short8v*)(hif + (size_t)i * 192);
  float acc = 0.f;
#pragma unroll
  for (int t = 0; t < 3; ++t){
    short8v a = hu[l8 + 8 * t];
    short8v b = hi[l8 + 8 * t];
#pragma unroll
    for (int j = 0; j < 8; ++j) acc += h2f(a[j]) * h2f(b[j]);
  }
#pragma unroll
  for (int o = 1; o < 8; o <<= 1) acc += __shfl_xor(acc, o, 64);
  if (l8 == 0) out[k] = acc;
}

// ---- f32 fallback scoring (used only if workspace too small for f16 tables) ----
__global__ void k_score(const int* __restrict__ pu, const int* __restrict__ pi,
                        const int* __restrict__ nu, const int* __restrict__ ni,
                        const float* __restrict__ hu_all, const float* __restrict__ hi_all,
                        float* __restrict__ out, int EP){
  int gw = blockIdx.x * 4 + (threadIdx.x >> 6);
  int sub = (threadIdx.x >> 4) & 3, l16 = threadIdx.x & 15;
  int k = gw * 4 + sub;
  if (k >= 2 * EP) return;
  int u, i;
  if (k < EP){ u = pu[k]; i = pi[k]; } else { u = nu[k - EP]; i = ni[k - EP]; }
  const float4* hu = (const float4*)(hu_all + (size_t)u * 192);
  const float4* hi = (const float4*)(hi_all + (size_t)i * 192);
  float acc = 0.f;
#pragma unroll
  for (int t = 0; t < 3; ++t){
    float4 a = hu[l16 + 16 * t];
    float4 b = hi[l16 + 16 * t];
    acc += a.x * b.x + a.y * b.y + a.z * b.z + a.w * b.w;
  }
#pragma unroll
  for (int o = 8; o > 0; o >>= 1) acc += __shfl_xor(acc, o, 64);
  if (l16 == 0) out[k] = acc;
}

extern "C" void kernel_launch(void* const* d_in, const int* in_sizes, int n_in,
                              void* d_out, int out_size, void* d_ws, size_t ws_size,
                              hipStream_t stream) {
  const int*   rate_src  = (const int*)  d_in[0];
  const int*   rate_dst  = (const int*)  d_in[1];
  const int*   trust_src = (const int*)  d_in[2];
  const int*   trust_dst = (const int*)  d_in[3];
  const int*   pos_u     = (const int*)  d_in[4];
  const int*   pos_i     = (const int*)  d_in[5];
  const int*   neg_u     = (const int*)  d_in[6];
  const int*   neg_i     = (const int*)  d_in[7];
  const float* eu        = (const float*)d_in[8];
  const float* ei        = (const float*)d_in[9];
  const float* rate_W    = (const float*)d_in[10];
  const float* rate_b    = (const float*)d_in[11];
  const float* rate_attn = (const float*)d_in[12];
  const float* rate_bias = (const float*)d_in[13];
  const float* rb_W      = (const float*)d_in[14];
  const float* rb_b      = (const float*)d_in[15];
  const float* rb_attn   = (const float*)d_in[16];
  const float* rb_bias   = (const float*)d_in[17];
  const float* tr_W      = (const float*)d_in[18];
  const float* tr_b      = (const float*)d_in[19];
  const float* tr_attn   = (const float*)d_in[20];
  const float* tr_bias   = (const float*)d_in[21];
  const float* attW1     = (const float*)d_in[22];
  const float* attb1     = (const float*)d_in[23];
  const float* attW2     = (const float*)d_in[24];
  const float* attb2     = (const float*)d_in[25];

  const int ER = in_sizes[0];
  const int ET = in_sizes[2];
  const int EP = in_sizes[4];
  const int NU = in_sizes[8] / 64;
  const int NI = in_sizes[9] / 64;
  const int EM = (ER > ET) ? ER : ET;

  // ---- workspace layout (aliasing: pos arrays in table region, NI tables in p) ----
  float* ws = (float*)d_ws;
  float*  hu_all = ws;                                   // NU*192 f32
  float*  hi_all = hu_all + (size_t)NU * 192;            // NI*192
  float*  p      = hi_all + (size_t)NI * 192;            // NU*64 f32
  float*  q      = p + (size_t)NU * 64;                  // NU*64 f32
  bf16*   tb     = (bf16*)(q + (size_t)NU * 64);         // NU*256 bf16 (4 NU-tables)
  bf16*   fsA    = tb;                                   // NU*64
  bf16*   fdB    = tb + (size_t)NU * 64;                 // NU*64
  bf16*   fsC    = tb + (size_t)NU * 128;                // NU*64
  bf16*   fdC    = tb + (size_t)NU * 192;                // NU*64
  bf16*   fdA    = (bf16*)p;                             // NI*64 (alias: dead before p written)
  bf16*   fsB    = (bf16*)p + (size_t)NI * 64;           // NI*64 (alias)
  u16*    posA   = (u16*)fsA;                            // ER u16 (alias: CSR build phase)
  u16*    posB   = (u16*)fdB;                            // ER u16
  u16*    posC   = (u16*)fsC;                            // ET u16
  float*  z1     = (float*)(tb + (size_t)NU * 256);      // NU
  float*  z2     = z1 + NU;                              // NU
  float*  bsums  = z2 + NU;                              // cdiv(NU,4)*4
  float*  vvec   = bsums + (size_t)(((NU + 3) / 4) * 4); // 512
  float*  cs     = vvec + 512;                           // 4
  double* sums   = (double*)(((uintptr_t)(cs + 4) + 15) & ~(uintptr_t)15); // 4
  double* gpart  = sums + 4;                             // 128*4
  short*  Whi    = (short*)(gpart + 512);                // 12*4096
  short*  Wlo    = Whi + 12 * 4096;                      // 12*4096
  int*    iw     = (int*)(Wlo + 12 * 4096);
  int*    cntA   = iw;                 // NI
  int*    cntB   = cntA + NI;          // NU
  int*    cntC   = cntB + NU;          // NU
  int*    gbase  = cntC + NU;          // 4 (3 used)
  int*    offsA  = gbase + 4;          // NI
  int*    offsB  = offsA + NI;         // NU
  int*    offsC  = offsB + NU;         // NU
  int*    csrA   = offsC + NU;         // ER
  int*    csrB   = csrA + ER;          // ER
  int*    csrC   = csrB + ER;          // ET
  // fp16 score tables appended past prior peak, 16B aligned
  uintptr_t fp16base = ((uintptr_t)(csrC + ET) + 15) & ~(uintptr_t)15;
  __half* huf = (__half*)fp16base;                       // NU*192 f16
  __half* hif = huf + (size_t)NU * 192;                  // NI*192 f16
  size_t need = (uintptr_t)(hif + (size_t)NI * 192) - (uintptr_t)d_ws;
  bool use_f16 = (need <= ws_size);

  auto cdiv = [](int a, int b){ return (a + b - 1) / b; };
  const int nbz = cdiv(NU, 4);

  // ---- one-time per call ----
  k_copy_in2<<<cdiv((NU + NI) * 16, 256), 256, 0, stream>>>(eu, ei, hu_all, hi_all,
      use_f16 ? huf : (__half*)nullptr, use_f16 ? hif : (__half*)nullptr, NU, NI);
  k_attvec<<<1, 512, 0, stream>>>(attW1, attb1, attW2, attb2, vvec, cs);
  k_wsplit<<<192, 256, 0, stream>>>(rate_W, rb_W, tr_W, Whi, Wlo);

  hipMemsetAsync(cntA, 0, (size_t)(NI + 2 * NU + 4) * 4, stream);
  k_hist_all<<<cdiv(EM, 256), 256, 0, stream>>>(rate_src, rate_dst, trust_dst,
      cntA, cntB, cntC, posA, posB, posC, ER, ET);
  k_scan_mb<<<cdiv(NI, 1024), 1024, 0, stream>>>(cntA, NI, offsA, gbase + 0);
  k_scan_mb<<<cdiv(NU, 1024), 1024, 0, stream>>>(cntB, NU, offsB, gbase + 1);
  k_scan_mb<<<cdiv(NU, 1024), 1024, 0, stream>>>(cntC, NU, offsC, gbase + 2);
  k_fill_all<<<cdiv(EM, 256), 256, 0, stream>>>(rate_src, rate_dst, trust_src, trust_dst,
      offsA, posA, csrA, offsB, posB, csrB, offsC, posC, csrC, ER, ET);

  for (int l = 0; l < 2; ++l){
    // fused linears: NU side (4 outputs from one hu read), NI side (2 outputs)
    // m = rel*4 + l*2 + io; rel: rate=0, rb=1, tr=2
    k_linear_multi<<<cdiv(NU, 64), 256, 0, stream>>>(hu_all, 192, l * 64, NU, Whi, Wlo, 4,
        0 + l * 2 + 0, rate_b + (l * 2 + 0) * 64, fsA,     // rate src
        4 + l * 2 + 1, rb_b   + (l * 2 + 1) * 64, fdB,     // rb dst
        8 + l * 2 + 0, tr_b   + (l * 2 + 0) * 64, fsC,     // tr src
        8 + l * 2 + 1, tr_b   + (l * 2 + 1) * 64, fdC);    // tr dst
    k_linear_multi<<<cdiv(NI, 64), 256, 0, stream>>>(hi_all, 192, l * 64, NI, Whi, Wlo, 2,
        0 + l * 2 + 1, rate_b + (l * 2 + 1) * 64, fdA,     // rate dst
        4 + l * 2 + 0, rb_b   + (l * 2 + 0) * 64, fsB,     // rb src
        0, (const float*)nullptr, (bf16*)nullptr,
        0, (const float*)nullptr, (bf16*)nullptr);

    // rate GAT: users -> items, into hi_all block l+1 (+bias+residual, + f16 table)
    k_gat<<<cdiv(NI, 4), 256, 0, stream>>>(offsA, cntA, csrA, fsA, fdA,
        rate_attn + l * 64, rate_bias + l * 64,
        hi_all, 192, (l + 1) * 64, hi_all, 192, l * 64,
        use_f16 ? (hif + (size_t)(l + 1) * 64) : (__half*)nullptr, NI);
    // rated-by GAT: items -> users -> q
    k_gat<<<cdiv(NU, 4), 256, 0, stream>>>(offsB, cntB, csrB, fsB, fdB,
        rb_attn + l * 64, rb_bias + l * 64,
        q, 64, 0, (const float*)nullptr, 0, 0, (__half*)nullptr, NU);
    // trust GAT: users -> users -> p (p overwrites fdA/fsB aliases: both dead now)
    k_gat<<<cdiv(NU, 4), 256, 0, stream>>>(offsC, cntC, csrC, fsC, fdC,
        tr_attn + l * 64, tr_bias + l * 64,
        p, 64, 0, (const float*)nullptr, 0, 0, (__half*)nullptr, NU);

    // attention gate + combine -> hu_all block l+1 (+ f16 table)
    k_gate_z<<<nbz, 256, 0, stream>>>(hu_all, l, p, q, vvec, cs, z1, z2, bsums, NU);
    k_bn_part<<<128, 256, 0, stream>>>(bsums, nbz, gpart);
    k_bn_final<<<1, 256, 0, stream>>>(gpart, 128, sums);
    // f32 block l+1 needed downstream only for l==0 (linears/gate_z of layer 1)
    int wf32 = (!use_f16 || l == 0) ? 1 : 0;
    k_gate_combine<<<cdiv(NU * 64, 256), 256, 0, stream>>>(hu_all, l, p, q, z1, z2, sums,
        use_f16 ? (huf + (size_t)(l + 1) * 64) : (__half*)nullptr, wf32, NU);
  }

  // ---- final scoring ----
  if (use_f16)
    k_score_f16<<<cdiv(2 * EP, 32), 256, 0, stream>>>(pos_u, pos_i, neg_u, neg_i,
        huf, hif, (float*)d_out, EP);
  else
    k_score<<<cdiv(2 * EP, 16), 256, 0, stream>>>(pos_u, pos_i, neg_u, neg_i,
        hu_all, hi_all, (float*)d_out, EP);
}

// Round 2
// 911.792 us; speedup vs baseline: 1.0983x; 1.0542x over previous
//
#include <hip/hip_runtime.h>
#include <hip/hip_bf16.h>
#include <hip/hip_fp16.h>
#include <cstdint>

typedef __hip_bfloat16 bf16;
typedef __attribute__((ext_vector_type(8))) short frag_ab;   // 8 bf16 (4 VGPRs)
typedef __attribute__((ext_vector_type(4))) float frag_cd;   // 4 fp32
typedef __attribute__((ext_vector_type(4))) short short4v;   // 4 x 16-bit
typedef __attribute__((ext_vector_type(8))) short short8v;   // 8 x 16-bit (16B)
typedef unsigned short u16;

__device__ __forceinline__ float b2f(short s){
  return __uint_as_float(((unsigned)(unsigned short)s) << 16);
}
__device__ __forceinline__ float h2f(short s){
  __half h; __builtin_memcpy(&h, &s, 2); return __half2float(h);
}
__device__ __forceinline__ short f2h_s(float x){
  __half h = __float2half(x);
  short s; __builtin_memcpy(&s, &h, 2); return s;
}
__device__ __forceinline__ void bf_split(float x, short& hi, short& lo){
  bf16 h = __float2bfloat16(x);
  float hf = __bfloat162float(h);
  bf16 l = __float2bfloat16(x - hf);
  __builtin_memcpy(&hi, &h, 2);
  __builtin_memcpy(&lo, &l, 2);
}

__device__ __forceinline__ float wave_sum(float v){
#pragma unroll
  for (int o = 32; o > 0; o >>= 1) v += __shfl_down(v, o, 64);
  return v;
}

// ================= fused prep: hist || copy-in || wsplit || attvec =================
struct PrepArgs {
  int NBH, NBC, ER, ET, NU, NI;
  const int *rate_src, *rate_dst, *trust_dst;
  int *cntA, *cntB, *cntC;
  u16 *posA, *posB, *posC;
  const float *eu, *ei;
  float *hu, *hi;
  __half *huf, *hif;
  const float *rateW, *rbW, *trW;
  short *Whi, *Wlo;
  const float *W1, *b1, *W2, *b2;
  float *vvec, *cs;
};

__global__ void k_prep(PrepArgs a){
  int b = blockIdx.x, t = threadIdx.x;
  if (b < a.NBH){
    // -------- histogram + per-edge position (atomic-bound) --------
    int k = b * 256 + t;
    if (k < a.ER){
      int d = a.rate_dst[k], s = a.rate_src[k];
      a.posA[k] = (u16)atomicAdd(a.cntA + d, 1);
      a.posB[k] = (u16)atomicAdd(a.cntB + s, 1);
    }
    if (k < a.ET){
      a.posC[k] = (u16)atomicAdd(a.cntC + a.trust_dst[k], 1);
    }
    return;
  }
  b -= a.NBH;
  if (b < a.NBC){
    // -------- copy-in: eu/ei [n,64] -> [n,192] f32 (+opt f16), 4 float4/thread --------
    int tot = (a.NU + a.NI) * 16;
    int tu = a.NU * 16;
    int base = b * 1024 + t;
#pragma unroll
    for (int s = 0; s < 4; ++s){
      int idx = base + s * 256;
      if (idx >= tot) break;
      const float* srcp; float* dstp; __half* fp_; int r, jj;
      if (idx < tu){ r = idx >> 4; jj = idx & 15; srcp = a.eu; dstp = a.hu; fp_ = a.huf; }
      else { int t2 = idx - tu; r = t2 >> 4; jj = t2 & 15; srcp = a.ei; dstp = a.hi; fp_ = a.hif; }
      float4 v = *(const float4*)(srcp + (size_t)r * 64 + 4 * jj);
      *(float4*)(dstp + (size_t)r * 192 + 4 * jj) = v;
      if (fp_){
        short4v h;
        h[0] = f2h_s(v.x); h[1] = f2h_s(v.y); h[2] = f2h_s(v.z); h[3] = f2h_s(v.w);
        *(short4v*)((short*)fp_ + (size_t)r * 192 + 4 * jj) = h;
      }
    }
    return;
  }
  b -= a.NBC;
  if (b < 192){
    // -------- wsplit: 12 W matrices -> MFMA-fragment bf16 hi/lo --------
    int tid = b * 256 + t;                           // < 12*4096 = 49152
    int m = tid >> 12, rem = tid & 4095;
    int lane = rem >> 6, rem2 = rem & 63;
    int pair = rem2 >> 3, j = rem2 & 7;
    int c = pair >> 1, h = pair & 1;
    int rel = m >> 2, li = m & 3;                    // li = l*2+io
    const float* base = (rel == 0) ? a.rateW : (rel == 1) ? a.rbW : a.trW;
    float v = base[(size_t)li * 4096 + (32 * h + (lane >> 4) * 8 + j) * 64 + 16 * c + (lane & 15)];
    short sh, sl; bf_split(v, sh, sl);
    a.Whi[tid] = sh; a.Wlo[tid] = sl;
    return;
  }
  // -------- attvec: collapse gate MLP (512 items on 256 threads) --------
  for (int it = t; it < 512; it += 256){
    int li = it >> 7, r = it & 127;
    float acc = 0.f;
    for (int c = 0; c < 128; ++c)
      acc += a.W1[(size_t)(li * 128 + r) * 128 + c] * a.W2[li * 128 + c];
    a.vvec[li * 128 + r] = acc;
    if (r == 0){
      float cacc = a.b2[li];
      for (int c = 0; c < 128; ++c)
        cacc += a.b1[li * 128 + c] * a.W2[li * 128 + c];
      a.cs[li] = cacc;
    }
  }
}

// ================= fused 3-way exclusive scan =================
__device__ __forceinline__ void dev_scan(int lb, const int* __restrict__ cnt, int n,
                                         int* __restrict__ offs, int* __restrict__ gbase){
  __shared__ int wsum[16];
  __shared__ int base_sh;
  int t = threadIdx.x, lane = t & 63, w = t >> 6;
  int i = lb * 1024 + t;
  int v = (i < n) ? cnt[i] : 0;
  int x = v;
#pragma unroll
  for (int o = 1; o < 64; o <<= 1){
    int y = __shfl_up(x, o, 64);
    if (lane >= o) x += y;
  }
  if (lane == 63) wsum[w] = x;
  __syncthreads();
  if (t == 0){
    int tot = 0;
    for (int k = 0; k < 16; ++k){ int c = wsum[k]; wsum[k] = tot; tot += c; }
    base_sh = atomicAdd(gbase, tot);
  }
  __syncthreads();
  if (i < n) offs[i] = base_sh + wsum[w] + x - v;
}

__global__ void k_scan3(int S0, int S1,
                        const int* cntA, int NI, int* offsA,
                        const int* cntB, int NU, int* offsB,
                        const int* cntC, int* offsC, int* gbase){
  int b = blockIdx.x;
  if (b < S0){ dev_scan(b, cntA, NI, offsA, gbase + 0); return; }
  b -= S0;
  if (b < S1){ dev_scan(b, cntB, NU, offsB, gbase + 1); return; }
  b -= S1;
  dev_scan(b, cntC, NU, offsC, gbase + 2);
}

// ================= fused CSR fill || linears =================
__device__ __forceinline__ void dev_linear(int blk, const float* __restrict__ x, int xs, int xo,
                                           int n, const short* __restrict__ Whi,
                                           const short* __restrict__ Wlo, int mcount,
                                           int m0, int m1, int m2, int m3,
                                           const float* b0, const float* b1,
                                           const float* b2, const float* b3,
                                           bf16* o0, bf16* o1, bf16* o2, bf16* o3){
  int lane = threadIdx.x & 63, w = threadIdx.x >> 6;
  int quad = lane >> 4, n16 = lane & 15;
  int rowbase = blk * 64 + w * 16;
  if (rowbase >= n) return;
  int lrow = rowbase + n16; if (lrow >= n) lrow = n - 1;   // clamp (stores guarded)
  const float* xp = x + (size_t)lrow * xs + xo;
  frag_ab ahi[2], alo[2];
#pragma unroll
  for (int h = 0; h < 2; ++h){
    frag_ab vh, vl;
#pragma unroll
    for (int j = 0; j < 8; ++j){
      float xv = xp[32 * h + quad * 8 + j];
      short sh, sl; bf_split(xv, sh, sl);
      vh[j] = sh; vl[j] = sl;
    }
    ahi[h] = vh; alo[h] = vl;
  }
  int ms[4] = {m0, m1, m2, m3};
  const float* bs[4] = {b0, b1, b2, b3};
  bf16* os[4] = {o0, o1, o2, o3};
  for (int i = 0; i < mcount; ++i){
    const frag_ab* Bh = (const frag_ab*)(Whi + (size_t)ms[i] * 4096 + lane * 64);
    const frag_ab* Bl = (const frag_ab*)(Wlo + (size_t)ms[i] * 4096 + lane * 64);
    frag_cd acc[4];
#pragma unroll
    for (int c = 0; c < 4; ++c) acc[c] = frag_cd{0.f, 0.f, 0.f, 0.f};
#pragma unroll
    for (int c = 0; c < 4; ++c)
#pragma unroll
      for (int h = 0; h < 2; ++h){
        frag_ab bh = Bh[c * 2 + h], bl = Bl[c * 2 + h];
        acc[c] = __builtin_amdgcn_mfma_f32_16x16x32_bf16(ahi[h], bh, acc[c], 0, 0, 0);
        acc[c] = __builtin_amdgcn_mfma_f32_16x16x32_bf16(alo[h], bh, acc[c], 0, 0, 0);
        acc[c] = __builtin_amdgcn_mfma_f32_16x16x32_bf16(ahi[h], bl, acc[c], 0, 0, 0);
      }
    const float* bb = bs[i];
    bf16* oo = os[i];
#pragma unroll
    for (int reg = 0; reg < 4; ++reg){
      int r = rowbase + quad * 4 + reg;
      if (r >= n) continue;
#pragma unroll
      for (int c = 0; c < 4; ++c)
        oo[(size_t)r * 64 + 16 * c + n16] = __float2bfloat16(acc[c][reg] + bb[16 * c + n16]);
    }
  }
}

struct FillArgs {
  int NBF, ER, ET;
  const int *rs_, *rd_, *ts_, *td_;
  const int *offsA; const u16 *posA; int *csrA;
  const int *offsB; const u16 *posB; int *csrB;
  const int *offsC; const u16 *posC; int *csrC;
};
struct LinArgs {
  int nblk; const float* x; int xs, xo, n, mcount;
  int m0, m1, m2, m3;
  const float *b0, *b1, *b2, *b3;
  bf16 *o0, *o1, *o2, *o3;
};

__global__ void k_fill_lin(FillArgs F, LinArgs LU, LinArgs LI){
  int b = blockIdx.x;
  if (b < F.NBF){
    int k = b * 256 + threadIdx.x;
    if (k < F.ER){
      int s = F.rs_[k], d = F.rd_[k];
      F.csrA[F.offsA[d] + (int)F.posA[k]] = s;
      F.csrB[F.offsB[s] + (int)F.posB[k]] = d;
    }
    if (k < F.ET){
      int s = F.ts_[k], d = F.td_[k];
      F.csrC[F.offsC[d] + (int)F.posC[k]] = s;
    }
    return;
  }
  b -= F.NBF;
  if (b < LU.nblk){
    dev_linear(b, LU.x, LU.xs, LU.xo, LU.n, nullptr, nullptr, 0,
               0, 0, 0, 0, nullptr, nullptr, nullptr, nullptr,
               nullptr, nullptr, nullptr, nullptr);
  }
  // NOTE: dev_linear needs Whi/Wlo; real dispatch below (kept single call sites)
}

// (the above placeholder overload removed; real fused kernel:)
struct FillLinArgs {
  FillArgs F;
  const short *Whi, *Wlo;
  LinArgs LU, LI;
};
__global__ void k_fill_lin2(FillLinArgs A){
  int b = blockIdx.x;
  if (b < A.F.NBF){
    int k = b * 256 + threadIdx.x;
    if (k < A.F.ER){
      int s = A.F.rs_[k], d = A.F.rd_[k];
      A.F.csrA[A.F.offsA[d] + (int)A.F.posA[k]] = s;
      A.F.csrB[A.F.offsB[s] + (int)A.F.posB[k]] = d;
    }
    if (k < A.F.ET){
      int s = A.F.ts_[k], d = A.F.td_[k];
      A.F.csrC[A.F.offsC[d] + (int)A.F.posC[k]] = s;
    }
    return;
  }
  b -= A.F.NBF;
  if (b < A.LU.nblk){
    dev_linear(b, A.LU.x, A.LU.xs, A.LU.xo, A.LU.n, A.Whi, A.Wlo, A.LU.mcount,
               A.LU.m0, A.LU.m1, A.LU.m2, A.LU.m3,
               A.LU.b0, A.LU.b1, A.LU.b2, A.LU.b3,
               A.LU.o0, A.LU.o1, A.LU.o2, A.LU.o3);
    return;
  }
  b -= A.LU.nblk;
  if (b < A.LI.nblk){
    dev_linear(b, A.LI.x, A.LI.xs, A.LI.xo, A.LI.n, A.Whi, A.Wlo, A.LI.mcount,
               A.LI.m0, A.LI.m1, A.LI.m2, A.LI.m3,
               A.LI.b0, A.LI.b1, A.LI.b2, A.LI.b3,
               A.LI.o0, A.LI.o1, A.LI.o2, A.LI.o3);
  }
}

// ================= fused 3-GAT: 8 lanes/edge, 8 edges/wave =================
struct GatArgs {
  int nblk, n;
  const int *offs, *cnt, *csr;
  const bf16 *fs, *fd;
  const float *attn, *bias;
  float *out; int os, oo;
  const float *res; int rs, ro;
  __half *fout;
};

__device__ __forceinline__ void dev_gat(int lb, const GatArgs& g){
  int d = lb * 4 + (threadIdx.x >> 6);
  if (d >= g.n) return;
  int lane = threadIdx.x & 63;
  int gg = lane >> 3, l8 = lane & 7;          // 8 groups x 8 lanes
  short8v dv = *(const short8v*)(g.fd + (size_t)d * 64 + 8 * l8);
  float fdv[8];
#pragma unroll
  for (int j = 0; j < 8; ++j) fdv[j] = b2f(dv[j]);
  float4 a0 = *(const float4*)(g.attn + 8 * l8);
  float4 a1 = *(const float4*)(g.attn + 8 * l8 + 4);
  float a8[8] = {a0.x, a0.y, a0.z, a0.w, a1.x, a1.y, a1.z, a1.w};
  float acc[8];
#pragma unroll
  for (int j = 0; j < 8; ++j) acc[j] = 0.f;
  float den = 0.f;
  int idx0 = g.offs[d], end = idx0 + g.cnt[d];
  for (int idx = idx0; idx < end; idx += 8){
    int e = idx + gg;
    bool valid = e < end;
    int s = g.csr[valid ? e : idx];
    short8v sv = *(const short8v*)(g.fs + (size_t)s * 64 + 8 * l8);
    float f[8];
    float tt = 0.f;
#pragma unroll
    for (int j = 0; j < 8; ++j){
      f[j] = b2f(sv[j]);
      float v = f[j] + fdv[j];
      v = (v > 0.f) ? v : 0.2f * v;
      tt += v * a8[j];
    }
#pragma unroll
    for (int o = 1; o < 8; o <<= 1) tt += __shfl_xor(tt, o, 64);
    float ex = valid ? __expf(tt) : 0.f;
#pragma unroll
    for (int j = 0; j < 8; ++j) acc[j] += ex * f[j];
    den += ex;
  }
#pragma unroll
  for (int o = 8; o < 64; o <<= 1){
#pragma unroll
    for (int j = 0; j < 8; ++j) acc[j] += __shfl_xor(acc[j], o, 64);
    den += __shfl_xor(den, o, 64);
  }
  if (gg == 0){
    float inv = (den > 0.f) ? 1.f / den : 0.f;
    float4 b0 = *(const float4*)(g.bias + 8 * l8);
    float4 b1 = *(const float4*)(g.bias + 8 * l8 + 4);
    float o8[8];
    o8[0] = acc[0] * inv + b0.x; o8[1] = acc[1] * inv + b0.y;
    o8[2] = acc[2] * inv + b0.z; o8[3] = acc[3] * inv + b0.w;
    o8[4] = acc[4] * inv + b1.x; o8[5] = acc[5] * inv + b1.y;
    o8[6] = acc[6] * inv + b1.z; o8[7] = acc[7] * inv + b1.w;
    if (g.res){
      float4 r0 = *(const float4*)(g.res + (size_t)d * g.rs + g.ro + 8 * l8);
      float4 r1 = *(const float4*)(g.res + (size_t)d * g.rs + g.ro + 8 * l8 + 4);
      o8[0] += r0.x; o8[1] += r0.y; o8[2] += r0.z; o8[3] += r0.w;
      o8[4] += r1.x; o8[5] += r1.y; o8[6] += r1.z; o8[7] += r1.w;
    }
    *(float4*)(g.out + (size_t)d * g.os + g.oo + 8 * l8) = make_float4(o8[0], o8[1], o8[2], o8[3]);
    *(float4*)(g.out + (size_t)d * g.os + g.oo + 8 * l8 + 4) = make_float4(o8[4], o8[5], o8[6], o8[7]);
    if (g.fout){
      short8v hv;
#pragma unroll
      for (int j = 0; j < 8; ++j) hv[j] = f2h_s(o8[j]);
      *(short8v*)((short*)g.fout + (size_t)d * 192 + 8 * l8) = hv;
    }
  }
}

__global__ void k_gat3(GatArgs A, GatArgs B, GatArgs C){
  int b = blockIdx.x;
  if (b < A.nblk){ dev_gat(b, A); return; }
  b -= A.nblk;
  if (b < B.nblk){ dev_gat(b, B); return; }
  b -= B.nblk;
  dev_gat(b, C);
}

// ---- gate z-scores + per-block partial sums (p lives in hu_all block l+1) ----
__global__ void k_gate_z(const float* __restrict__ hu_all, int l,
                         const float* __restrict__ q,
                         const float* __restrict__ vvec, const float* __restrict__ cs,
                         float* __restrict__ z1, float* __restrict__ z2,
                         float* __restrict__ bsums, int n){
  __shared__ float part[4][4];
  int w = threadIdx.x >> 6, j = threadIdx.x & 63;
  int nidx = blockIdx.x * 4 + w;
  float lz1 = 0.f, lz2 = 0.f;
  if (nidx < n){
    const float* v1 = vvec + l * 256;
    const float* v2 = vvec + l * 256 + 128;
    float h  = hu_all[(size_t)nidx * 192 + l * 64 + j];
    float pv = hu_all[(size_t)nidx * 192 + (l + 1) * 64 + j];
    float qv = q[(size_t)nidx * 64 + j];
    float t1 = wave_sum(h * v1[j] + pv * v1[64 + j]);
    float t2 = wave_sum(h * v2[j] + qv * v2[64 + j]);
    if (j == 0){
      lz1 = t1 + cs[l * 2 + 0];
      lz2 = t2 + cs[l * 2 + 1];
      z1[nidx] = lz1;
      z2[nidx] = lz2;
    }
  }
  if (j == 0){
    part[w][0] = lz1; part[w][1] = lz1 * lz1;
    part[w][2] = lz2; part[w][3] = lz2 * lz2;
  }
  __syncthreads();
  if (threadIdx.x < 4)
    bsums[(size_t)blockIdx.x * 4 + threadIdx.x] =
        part[0][threadIdx.x] + part[1][threadIdx.x] +
        part[2][threadIdx.x] + part[3][threadIdx.x];
}

// ---- fused BN reduce: 128 blocks partial + last-block final (ticket) ----
__global__ void k_bn(const float* __restrict__ bsums, int nb,
                     double* __restrict__ gpart, double* __restrict__ sums,
                     int* __restrict__ tick){
  __shared__ double sh[256];
  __shared__ int lastflag;
  int c = threadIdx.x & 3, r0 = blockIdx.x * 64 + (threadIdx.x >> 2);
  double acc = 0.0;
  for (int i = r0; i < nb; i += gridDim.x * 64)
    acc += (double)bsums[(size_t)i * 4 + c];
  sh[threadIdx.x] = acc;
  __syncthreads();
  for (int s = 128; s >= 4; s >>= 1){
    if (threadIdx.x < s) sh[threadIdx.x] += sh[threadIdx.x + s];
    __syncthreads();
  }
  if (threadIdx.x < 4) gpart[(size_t)blockIdx.x * 4 + threadIdx.x] = sh[threadIdx.x];
  __threadfence();
  if (threadIdx.x == 0) lastflag = (atomicAdd(tick, 1) == (int)gridDim.x - 1);
  __syncthreads();
  if (lastflag){
    __threadfence();
    int k0 = threadIdx.x >> 2;
    double a2 = 0.0;
    for (int i = k0; i < (int)gridDim.x; i += 64) a2 += gpart[(size_t)i * 4 + c];
    sh[threadIdx.x] = a2;
    __syncthreads();
    for (int s = 128; s >= 4; s >>= 1){
      if (threadIdx.x < s) sh[threadIdx.x] += sh[threadIdx.x + s];
      __syncthreads();
    }
    if (threadIdx.x < 4) sums[threadIdx.x] = sh[threadIdx.x];
  }
}

// ---- BN + lrelu + softmax gate + combine; p read from (and overwritten in) block l+1 ----
__global__ void k_gate_combine(float* __restrict__ hu_all, int l,
                               const float* __restrict__ q,
                               const float* __restrict__ z1, const float* __restrict__ z2,
                               const double* __restrict__ sums,
                               __half* __restrict__ fout, int wf32, int n){
  int idx = blockIdx.x * 256 + threadIdx.x;
  if (idx >= n * 64) return;
  int r = idx >> 6, j = idx & 63;
  double invn = 1.0 / (double)n;
  double mu1 = sums[0] * invn, mu2 = sums[2] * invn;
  float var1 = (float)(sums[1] * invn - mu1 * mu1);
  float var2 = (float)(sums[3] * invn - mu2 * mu2);
  float rs1 = rsqrtf(var1 + 1e-5f), rs2 = rsqrtf(var2 + 1e-5f);
  float a1 = (z1[r] - (float)mu1) * rs1;
  float a2 = (z2[r] - (float)mu2) * rs2;
  a1 = a1 > 0.f ? a1 : 0.01f * a1;
  a2 = a2 > 0.f ? a2 : 0.01f * a2;
  float mx = fmaxf(a1, a2);
  float e1 = __expf(a1 - mx), e2 = __expf(a2 - mx);
  float inv = 1.f / (e1 + e2);
  float pv = hu_all[(size_t)r * 192 + (l + 1) * 64 + j];
  float out = (e1 * inv) * pv + (e2 * inv) * q[idx]
            + hu_all[(size_t)r * 192 + l * 64 + j];
  if (wf32) hu_all[(size_t)r * 192 + (l + 1) * 64 + j] = out;
  if (fout) *((short*)fout + (size_t)r * 192 + j) = f2h_s(out);
}

// ---- final scoring, fp16 tables ----
__global__ void k_score_f16(const int* __restrict__ pu, const int* __restrict__ pi,
                            const int* __restrict__ nu, const int* __restrict__ ni,
                            const __half* __restrict__ huf, const __half* __restrict__ hif,
                            float* __restrict__ out, int EP){
  int wv = threadIdx.x >> 6, lane = threadIdx.x & 63;
  int g = lane >> 3, l8 = lane & 7;
  int k = (blockIdx.x * 4 + wv) * 8 + g;
  if (k >= 2 * EP) return;
  int u, i;
  if (k < EP){ u = pu[k]; i = pi[k]; } else { u = nu[k - EP]; i = ni[k - EP]; }
  const short8v* hu = (const short8v*)(huf + (size_t)u * 192);
  const short8v* hi = (const short8v*)(hif + (size_t)i * 192);
  float acc = 0.f;
#pragma unroll
  for (int t = 0; t < 3; ++t){
    short8v a = hu[l8 + 8 * t];
    short8v b = hi[l8 + 8 * t];
#pragma unroll
    for (int j = 0; j < 8; ++j) acc += h2f(a[j]) * h2f(b[j]);
  }
#pragma unroll
  for (int o = 1; o < 8; o <<= 1) acc += __shfl_xor(acc, o, 64);
  if (l8 == 0) out[k] = acc;
}

// ---- f32 fallback scoring ----
__global__ void k_score(const int* __restrict__ pu, const int* __restrict__ pi,
                        const int* __restrict__ nu, const int* __restrict__ ni,
                        const float* __restrict__ hu_all, const float* __restrict__ hi_all,
                        float* __restrict__ out, int EP){
  int gw = blockIdx.x * 4 + (threadIdx.x >> 6);
  int sub = (threadIdx.x >> 4) & 3, l16 = threadIdx.x & 15;
  int k = gw * 4 + sub;
  if (k >= 2 * EP) return;
  int u, i;
  if (k < EP){ u = pu[k]; i = pi[k]; } else { u = nu[k - EP]; i = ni[k - EP]; }
  const float4* hu = (const float4*)(hu_all + (size_t)u * 192);
  const float4* hi = (const float4*)(hi_all + (size_t)i * 192);
  float acc = 0.f;
#pragma unroll
  for (int t = 0; t < 3; ++t){
    float4 a = hu[l16 + 16 * t];
    float4 b = hi[l16 + 16 * t];
    acc += a.x * b.x + a.y * b.y + a.z * b.z + a.w * b.w;
  }
#pragma unroll
  for (int o = 8; o > 0; o >>= 1) acc += __shfl_xor(acc, o, 64);
  if (l16 == 0) out[k] = acc;
}

extern "C" void kernel_launch(void* const* d_in, const int* in_sizes, int n_in,
                              void* d_out, int out_size, void* d_ws, size_t ws_size,
                              hipStream_t stream) {
  const int*   rate_src  = (const int*)  d_in[0];
  const int*   rate_dst  = (const int*)  d_in[1];
  const int*   trust_src = (const int*)  d_in[2];
  const int*   trust_dst = (const int*)  d_in[3];
  const int*   pos_u     = (const int*)  d_in[4];
  const int*   pos_i     = (const int*)  d_in[5];
  const int*   neg_u     = (const int*)  d_in[6];
  const int*   neg_i     = (const int*)  d_in[7];
  const float* eu        = (const float*)d_in[8];
  const float* ei        = (const float*)d_in[9];
  const float* rate_W    = (const float*)d_in[10];
  const float* rate_b    = (const float*)d_in[11];
  const float* rate_attn = (const float*)d_in[12];
  const float* rate_bias = (const float*)d_in[13];
  const float* rb_W      = (const float*)d_in[14];
  const float* rb_b      = (const float*)d_in[15];
  const float* rb_attn   = (const float*)d_in[16];
  const float* rb_bias   = (const float*)d_in[17];
  const float* tr_W      = (const float*)d_in[18];
  const float* tr_b      = (const float*)d_in[19];
  const float* tr_attn   = (const float*)d_in[20];
  const float* tr_bias   = (const float*)d_in[21];
  const float* attW1     = (const float*)d_in[22];
  const float* attb1     = (const float*)d_in[23];
  const float* attW2     = (const float*)d_in[24];
  const float* attb2     = (const float*)d_in[25];

  const int ER = in_sizes[0];
  const int ET = in_sizes[2];
  const int EP = in_sizes[4];
  const int NU = in_sizes[8] / 64;
  const int NI = in_sizes[9] / 64;
  const int EM = (ER > ET) ? ER : ET;

  // ---- workspace layout ----
  float* ws = (float*)d_ws;
  float*  hu_all = ws;                                   // NU*192 f32 (p aliases block l+1)
  float*  hi_all = hu_all + (size_t)NU * 192;            // NI*192
  float*  niT    = hi_all + (size_t)NI * 192;            // NI*64 floats: fdA+fsB bf16 tables
  bf16*   fdA    = (bf16*)niT;                           // NI*64
  bf16*   fsB    = fdA + (size_t)NI * 64;                // NI*64
  float*  q      = niT + (size_t)NI * 64;                // NU*64 f32
  u16*    posA   = (u16*)q;                              // ER u16 (alias: dead before q written)
  u16*    posB   = posA + ER;                            // ER u16
  u16*    posC   = posB + ER;                            // ET u16  (2ER+ET)*2B <= NU*256B ok
  bf16*   tb     = (bf16*)(q + (size_t)NU * 64);         // NU*256 bf16 (4 NU-tables)
  bf16*   fsA    = tb;                                   // NU*64
  bf16*   fdB    = tb + (size_t)NU * 64;                 // NU*64
  bf16*   fsC    = tb + (size_t)NU * 128;                // NU*64
  bf16*   fdC    = tb + (size_t)NU * 192;                // NU*64
  float*  z1     = (float*)(tb + (size_t)NU * 256);      // NU
  float*  z2     = z1 + NU;                              // NU
  float*  bsums  = z2 + NU;                              // cdiv(NU,4)*4
  float*  vvec   = bsums + (size_t)(((NU + 3) / 4) * 4); // 512
  float*  cs     = vvec + 512;                           // 4
  double* sums   = (double*)(((uintptr_t)(cs + 4) + 15) & ~(uintptr_t)15); // 4
  double* gpart  = sums + 4;                             // 128*4
  short*  Whi    = (short*)(gpart + 512);                // 12*4096
  short*  Wlo    = Whi + 12 * 4096;                      // 12*4096
  int*    iw     = (int*)(Wlo + 12 * 4096);
  int*    cntA   = iw;                 // NI
  int*    cntB   = cntA + NI;          // NU
  int*    cntC   = cntB + NU;          // NU
  int*    gbase  = cntC + NU;          // 4 (3 used)
  int*    tick   = gbase + 4;          // 4 (2 used)
  int*    offsA  = tick + 4;           // NI
  int*    offsB  = offsA + NI;         // NU
  int*    offsC  = offsB + NU;         // NU
  int*    csrA   = offsC + NU;         // ER
  int*    csrB   = csrA + ER;          // ER
  int*    csrC   = csrB + ER;          // ET
  // fp16 score tables appended past prior peak (opportunistic)
  uintptr_t fp16base = ((uintptr_t)(csrC + ET) + 15) & ~(uintptr_t)15;
  __half* huf = (__half*)fp16base;                       // NU*192 f16
  __half* hif = huf + (size_t)NU * 192;                  // NI*192 f16
  size_t need = (uintptr_t)(hif + (size_t)NI * 192) - (uintptr_t)d_ws;
  bool use_f16 = (need <= ws_size);

  auto cdiv = [](int a, int b){ return (a + b - 1) / b; };
  const int nbz = cdiv(NU, 4);

  // ---- prep: memset then fused hist||copy||wsplit||attvec ----
  hipMemsetAsync(cntA, 0, (size_t)(NI + 2 * NU + 8) * 4, stream);

  int NBH = cdiv(EM, 256);
  int NBC = cdiv((NU + NI) * 16, 1024);
  PrepArgs pa;
  pa.NBH = NBH; pa.NBC = NBC; pa.ER = ER; pa.ET = ET; pa.NU = NU; pa.NI = NI;
  pa.rate_src = rate_src; pa.rate_dst = rate_dst; pa.trust_dst = trust_dst;
  pa.cntA = cntA; pa.cntB = cntB; pa.cntC = cntC;
  pa.posA = posA; pa.posB = posB; pa.posC = posC;
  pa.eu = eu; pa.ei = ei; pa.hu = hu_all; pa.hi = hi_all;
  pa.huf = use_f16 ? huf : (__half*)nullptr;
  pa.hif = use_f16 ? hif : (__half*)nullptr;
  pa.rateW = rate_W; pa.rbW = rb_W; pa.trW = tr_W; pa.Whi = Whi; pa.Wlo = Wlo;
  pa.W1 = attW1; pa.b1 = attb1; pa.W2 = attW2; pa.b2 = attb2;
  pa.vvec = vvec; pa.cs = cs;
  k_prep<<<NBH + NBC + 192 + 1, 256, 0, stream>>>(pa);

  int S0 = cdiv(NI, 1024), S1 = cdiv(NU, 1024), S2 = cdiv(NU, 1024);
  k_scan3<<<S0 + S1 + S2, 1024, 0, stream>>>(S0, S1, cntA, NI, offsA,
                                             cntB, NU, offsB, cntC, offsC, gbase);

  for (int l = 0; l < 2; ++l){
    // ---- CSR fill (l==0 only) fused with both linears ----
    FillLinArgs fa;
    fa.F.NBF = (l == 0) ? cdiv(EM, 256) : 0;
    fa.F.ER = ER; fa.F.ET = ET;
    fa.F.rs_ = rate_src; fa.F.rd_ = rate_dst; fa.F.ts_ = trust_src; fa.F.td_ = trust_dst;
    fa.F.offsA = offsA; fa.F.posA = posA; fa.F.csrA = csrA;
    fa.F.offsB = offsB; fa.F.posB = posB; fa.F.csrB = csrB;
    fa.F.offsC = offsC; fa.F.posC = posC; fa.F.csrC = csrC;
    fa.Whi = Whi; fa.Wlo = Wlo;
    fa.LU.nblk = cdiv(NU, 64); fa.LU.x = hu_all; fa.LU.xs = 192; fa.LU.xo = l * 64;
    fa.LU.n = NU; fa.LU.mcount = 4;
    fa.LU.m0 = 0 + l * 2 + 0; fa.LU.m1 = 4 + l * 2 + 1;
    fa.LU.m2 = 8 + l * 2 + 0; fa.LU.m3 = 8 + l * 2 + 1;
    fa.LU.b0 = rate_b + (l * 2 + 0) * 64; fa.LU.b1 = rb_b + (l * 2 + 1) * 64;
    fa.LU.b2 = tr_b + (l * 2 + 0) * 64;   fa.LU.b3 = tr_b + (l * 2 + 1) * 64;
    fa.LU.o0 = fsA; fa.LU.o1 = fdB; fa.LU.o2 = fsC; fa.LU.o3 = fdC;
    fa.LI.nblk = cdiv(NI, 64); fa.LI.x = hi_all; fa.LI.xs = 192; fa.LI.xo = l * 64;
    fa.LI.n = NI; fa.LI.mcount = 2;
    fa.LI.m0 = 0 + l * 2 + 1; fa.LI.m1 = 4 + l * 2 + 0; fa.LI.m2 = 0; fa.LI.m3 = 0;
    fa.LI.b0 = rate_b + (l * 2 + 1) * 64; fa.LI.b1 = rb_b + (l * 2 + 0) * 64;
    fa.LI.b2 = nullptr; fa.LI.b3 = nullptr;
    fa.LI.o0 = fdA; fa.LI.o1 = fsB; fa.LI.o2 = nullptr; fa.LI.o3 = nullptr;
    k_fill_lin2<<<fa.F.NBF + fa.LU.nblk + fa.LI.nblk, 256, 0, stream>>>(fa);

    // ---- fused 3-GAT ----
    GatArgs A, B, C;
    A.nblk = cdiv(NI, 4); A.n = NI;
    A.offs = offsA; A.cnt = cntA; A.csr = csrA; A.fs = fsA; A.fd = fdA;
    A.attn = rate_attn + l * 64; A.bias = rate_bias + l * 64;
    A.out = hi_all; A.os = 192; A.oo = (l + 1) * 64;
    A.res = hi_all; A.rs = 192; A.ro = l * 64;
    A.fout = use_f16 ? (hif + (size_t)(l + 1) * 64) : (__half*)nullptr;
    B.nblk = cdiv(NU, 4); B.n = NU;
    B.offs = offsB; B.cnt = cntB; B.csr = csrB; B.fs = fsB; B.fd = fdB;
    B.attn = rb_attn + l * 64; B.bias = rb_bias + l * 64;
    B.out = q; B.os = 64; B.oo = 0;
    B.res = nullptr; B.rs = 0; B.ro = 0; B.fout = nullptr;
    C.nblk = cdiv(NU, 4); C.n = NU;
    C.offs = offsC; C.cnt = cntC; C.csr = csrC; C.fs = fsC; C.fd = fdC;
    C.attn = tr_attn + l * 64; C.bias = tr_bias + l * 64;
    C.out = hu_all; C.os = 192; C.oo = (l + 1) * 64;   // p lives in block l+1
    C.res = nullptr; C.rs = 0; C.ro = 0; C.fout = nullptr;
    k_gat3<<<A.nblk + B.nblk + C.nblk, 256, 0, stream>>>(A, B, C);

    // ---- attention gate + BN + combine ----
    k_gate_z<<<nbz, 256, 0, stream>>>(hu_all, l, q, vvec, cs, z1, z2, bsums, NU);
    k_bn<<<128, 256, 0, stream>>>(bsums, nbz, gpart, sums, tick + l);
    int wf32 = (!use_f16 || l == 0) ? 1 : 0;
    k_gate_combine<<<cdiv(NU * 64, 256), 256, 0, stream>>>(hu_all, l, q, z1, z2, sums,
        use_f16 ? (huf + (size_t)(l + 1) * 64) : (__half*)nullptr, wf32, NU);
  }

  // ---- final scoring ----
  if (use_f16)
    k_score_f16<<<cdiv(2 * EP, 32), 256, 0, stream>>>(pos_u, pos_i, neg_u, neg_i,
        huf, hif, (float*)d_out, EP);
  else
    k_score<<<cdiv(2 * EP, 16), 256, 0, stream>>>(pos_u, pos_i, neg_u, neg_i,
        hu_all, hi_all, (float*)d_out, EP);
}